// Round 12
// baseline (465.363 us; speedup 1.0000x reference)
//
#include <hip/hip_runtime.h>
#include <math.h>

#define Bb   4
#define Nn   4096
#define Mm   4096
#define Dd   256
#define D0c  128
#define Kc   64

typedef _Float16 half8 __attribute__((ext_vector_type(8)));
typedef float    f32x4 __attribute__((ext_vector_type(4)));

__device__ __forceinline__ unsigned encf(float f) {
    unsigned u = __float_as_uint(f);
    return (u & 0x80000000u) ? ~u : (u | 0x80000000u);
}
__device__ __forceinline__ float decf(unsigned u) {
    return (u & 0x80000000u) ? __uint_as_float(u ^ 0x80000000u) : __uint_as_float(~u);
}
__device__ __forceinline__ float softplusf(float x) {
    return fmaxf(x, 0.f) + log1pf(expf(-fabsf(x)));
}
__device__ __forceinline__ void gl_lds16(const _Float16* g, _Float16* l) {
    __builtin_amdgcn_global_load_lds((const __attribute__((address_space(1))) void*)g,
                                     (__attribute__((address_space(3))) void*)l, 16, 0, 0);
}

// ---------------- prep: normalize rows, split fp16 hi/lo, tiled layout; init colMaxU
__global__ __launch_bounds__(256) void prep_kernel(
    const float* __restrict__ dA, const float* __restrict__ dB,
    _Float16* __restrict__ Ah, _Float16* __restrict__ Al,
    _Float16* __restrict__ Bh, _Float16* __restrict__ Bl,
    unsigned* __restrict__ colMaxU)
{
    const int t = threadIdx.x, wave = t >> 6, lane = t & 63;
    if (blockIdx.y == 0 && blockIdx.x < 64) colMaxU[blockIdx.x * 256 + t] = 0u;
    const int row = blockIdx.x * 4 + wave;           // 0..16383
    const float* src = blockIdx.y ? dB : dA;
    _Float16* dh = blockIdx.y ? Bh : Ah;
    _Float16* dl = blockIdx.y ? Bl : Al;
    const float4 v = *(const float4*)&src[(size_t)row * Dd + lane * 4];
    float ss = v.x * v.x + v.y * v.y + v.z * v.z + v.w * v.w;
#pragma unroll
    for (int m = 32; m; m >>= 1) ss += __shfl_xor(ss, m, 64);
    const float inv = 1.0f / sqrtf(ss);
    float x[4] = {v.x * inv, v.y * inv, v.z * inv, v.w * inv};
    union { _Float16 h[4]; uint2 u; } ph, pl;
#pragma unroll
    for (int i = 0; i < 4; i++) {
        _Float16 h = (_Float16)x[i];
        ph.h[i] = h;
        pl.h[i] = (_Float16)((x[i] - (float)h) * 4096.f);
    }
    const size_t toff = (size_t)(row >> 7) * 32768
                      + (size_t)(lane >> 3) * 4096
                      + (size_t)((lane >> 1) & 3) * 1024
                      + (size_t)(row & 127) * 8 + (lane & 1) * 4;
    *(uint2*)&dh[toff] = ph.u;
    *(uint2*)&dl[toff] = pl.u;
}

// ---------------- MFMA sim kernel ----------------
// PB=0: row/col exp-sum partials (+ optional nt-STORE of dot matrix for chunk)
// PB=1: argmax pass (fallback path only)
template<int PB, int STORE>
__global__ __launch_bounds__(256, 2) void sim_kernel(
    const _Float16* __restrict__ Ah, const _Float16* __restrict__ Al,
    const _Float16* __restrict__ Bh, const _Float16* __restrict__ Bl,
    const float* __restrict__ Lrow_g, const float* __restrict__ Lcol_g,
    float* __restrict__ rowsumP, float* __restrict__ colsumP,
    float* __restrict__ rkey, int* __restrict__ rmArr, float* __restrict__ rcvArr,
    unsigned* __restrict__ cmU, float* __restrict__ simG, int b0)
{
    __shared__ _Float16 lds[4][4][128][8];   // 32 KB
    __shared__ float    colp[128];
    __shared__ unsigned colu[128];
    __shared__ float    shL[128], shLc[128];

    const int t = threadIdx.x;
    const int wave = t >> 6, lane = t & 63;
    const int mt = blockIdx.x, nt = blockIdx.y, bbl = blockIdx.z;
    const int bb = b0 + bbl;
    const int n0 = nt * 128, m0 = mt * 128;

    if (PB) {
        if (t < 128) {
            shL[t]  = Lrow_g[bb * Nn + n0 + t];
            shLc[t] = Lcol_g[bb * Mm + m0 + t];
            colu[t] = 0u;
        }
    } else {
        if (t < 128) colp[t] = 0.f;
    }

    const _Float16* gb;
    {
        const size_t offA = (size_t)(bb * Nn + n0) * Dd;
        const size_t offB = (size_t)(bb * Mm + m0) * Dd;
        if      (wave == 0) gb = Ah + offA;
        else if (wave == 1) gb = Al + offA;
        else if (wave == 2) gb = Bh + offB;
        else                gb = Bl + offB;
    }

    f32x4 acc1[2][8], acc2[2][8];
#pragma unroll
    for (int ti = 0; ti < 2; ti++)
#pragma unroll
        for (int tj = 0; tj < 8; tj++) { acc1[ti][tj] = (f32x4)0.f; acc2[ti][tj] = (f32x4)0.f; }

    const int quad = lane >> 4, l15 = lane & 15;
    _Float16* ldsw = &lds[wave][0][0][0];

    for (int kc8 = 0; kc8 < 8; ++kc8) {
        const _Float16* gsrc = gb + kc8 * 4096;
#pragma unroll
        for (int q = 0; q < 8; ++q)
            gl_lds16(gsrc + q * 512 + lane * 8, ldsw + q * 512);
        __syncthreads();

        half8 afh[2], afl[2];
        afh[0] = *(const half8*)&lds[0][quad][wave * 32 + l15][0];
        afh[1] = *(const half8*)&lds[0][quad][wave * 32 + 16 + l15][0];
        afl[0] = *(const half8*)&lds[1][quad][wave * 32 + l15][0];
        afl[1] = *(const half8*)&lds[1][quad][wave * 32 + 16 + l15][0];
#pragma unroll
        for (int tj = 0; tj < 8; ++tj) {
            half8 bh = *(const half8*)&lds[2][quad][tj * 16 + l15][0];
            half8 bl = *(const half8*)&lds[3][quad][tj * 16 + l15][0];
#pragma unroll
            for (int ti = 0; ti < 2; ++ti) {
                acc1[ti][tj] = __builtin_amdgcn_mfma_f32_16x16x32_f16(afh[ti], bh, acc1[ti][tj], 0, 0, 0);
                acc2[ti][tj] = __builtin_amdgcn_mfma_f32_16x16x32_f16(afh[ti], bl, acc2[ti][tj], 0, 0, 0);
                acc2[ti][tj] = __builtin_amdgcn_mfma_f32_16x16x32_f16(afl[ti], bh, acc2[ti][tj], 0, 0, 0);
            }
        }
        __syncthreads();
    }

    if (!PB) {
        float rp[8] = {0.f}, cp[8] = {0.f};
#pragma unroll
        for (int ti = 0; ti < 2; ++ti)
#pragma unroll
            for (int tj = 0; tj < 8; ++tj)
#pragma unroll
                for (int r = 0; r < 4; ++r) {
                    float dot = fmaf(acc2[ti][tj][r], 2.44140625e-4f, acc1[ti][tj][r]);
                    acc1[ti][tj][r] = dot;
                    float e = __expf(fmaf(20.f, dot, -20.f));
                    rp[ti * 4 + r] += e;
                    cp[tj] += e;
                }
#pragma unroll
        for (int i = 0; i < 8; ++i)
#pragma unroll
            for (int m = 1; m < 16; m <<= 1) rp[i] += __shfl_xor(rp[i], m, 64);
        if (l15 == 0) {
#pragma unroll
            for (int ti = 0; ti < 2; ++ti)
#pragma unroll
                for (int r = 0; r < 4; ++r)
                    rowsumP[(size_t)(bb * 32 + mt) * Nn + n0 + wave * 32 + ti * 16 + quad * 4 + r] = rp[ti * 4 + r];
        }
#pragma unroll
        for (int tj = 0; tj < 8; ++tj) {
            cp[tj] += __shfl_xor(cp[tj], 16, 64);
            cp[tj] += __shfl_xor(cp[tj], 32, 64);
        }
        if (quad == 0) {
#pragma unroll
            for (int tj = 0; tj < 8; ++tj) atomicAdd(&colp[tj * 16 + l15], cp[tj]);
        }
        __syncthreads();
        if (t < 128) colsumP[(size_t)(bb * 32 + nt) * Mm + m0 + t] = colp[t];
        if (STORE) {
            // nontemporal: drain to HBM during this (MFMA-bound) kernel
            float* base = simG + ((size_t)bbl * Nn + n0) * Mm + m0;
#pragma unroll
            for (int ti = 0; ti < 2; ++ti)
#pragma unroll
                for (int r = 0; r < 4; ++r) {
                    float* rowp = base + (size_t)(wave * 32 + ti * 16 + quad * 4 + r) * Mm;
#pragma unroll
                    for (int tj = 0; tj < 8; ++tj)
                        __builtin_nontemporal_store(acc1[ti][tj][r], rowp + tj * 16 + l15);
                }
        }
    } else {
        float Lr[8];
#pragma unroll
        for (int ti = 0; ti < 2; ++ti)
#pragma unroll
            for (int r = 0; r < 4; ++r)
                Lr[ti * 4 + r] = shL[wave * 32 + ti * 16 + quad * 4 + r];

        float bk[8], bc[8];
        int bm[8];
        unsigned cu[8];
#pragma unroll
        for (int i = 0; i < 8; i++) { bk[i] = -INFINITY; bc[i] = -INFINITY; bm[i] = 0x7fffffff; }
#pragma unroll
        for (int j = 0; j < 8; j++) cu[j] = 0u;

#pragma unroll
        for (int ti = 0; ti < 2; ++ti)
#pragma unroll
            for (int tj = 0; tj < 8; ++tj)
#pragma unroll
                for (int r = 0; r < 4; ++r) {
                    float dot = fmaf(acc2[ti][tj][r], 2.44140625e-4f, acc1[ti][tj][r]);
                    float cv = fmaf(40.f, dot, -40.f - Lr[ti * 4 + r]);
                    float kv = cv - shLc[tj * 16 + l15];
                    const int i = ti * 4 + r;
                    if (kv > bk[i]) { bk[i] = kv; bm[i] = m0 + tj * 16 + l15; bc[i] = cv; }
                    unsigned e = encf(cv);
                    if (e > cu[tj]) cu[tj] = e;
                }
#pragma unroll
        for (int i = 0; i < 8; ++i) {
#pragma unroll
            for (int m = 1; m < 16; m <<= 1) {
                float okv = __shfl_xor(bk[i], m, 64);
                int   om  = __shfl_xor(bm[i], m, 64);
                float ocv = __shfl_xor(bc[i], m, 64);
                if (okv > bk[i] || (okv == bk[i] && om < bm[i])) { bk[i] = okv; bm[i] = om; bc[i] = ocv; }
            }
        }
        if (l15 == 0) {
#pragma unroll
            for (int ti = 0; ti < 2; ++ti)
#pragma unroll
                for (int r = 0; r < 4; ++r) {
                    const int i = ti * 4 + r;
                    size_t idx = (size_t)(bb * 32 + mt) * Nn + n0 + wave * 32 + ti * 16 + quad * 4 + r;
                    rkey[idx] = bk[i]; rmArr[idx] = bm[i]; rcvArr[idx] = bc[i];
                }
        }
#pragma unroll
        for (int tj = 0; tj < 8; ++tj) {
            unsigned o = __shfl_xor(cu[tj], 16, 64); if (o > cu[tj]) cu[tj] = o;
            o = __shfl_xor(cu[tj], 32, 64); if (o > cu[tj]) cu[tj] = o;
        }
        if (quad == 0) {
#pragma unroll
            for (int tj = 0; tj < 8; ++tj) atomicMax(&colu[tj * 16 + l15], cu[tj]);
        }
        __syncthreads();
        if (t < 128) cmU[(size_t)(bb * 32 + nt) * Mm + m0 + t] = colu[t];
    }
}

// ---------------- reduce partials -> L = log(rowsum), Lc = log(colsum), chunked -----
__global__ __launch_bounds__(256) void logsum_kernel(
    const float* __restrict__ rowsumP, const float* __restrict__ colsumP,
    float* __restrict__ Lrow, float* __restrict__ Lcol, int b0, int CB)
{
    int t = blockIdx.x * 256 + threadIdx.x;
    int half = CB * 4096;
    int which = t >= half;
    int idx = which ? (t - half) : t;
    int bb = b0 + (idx >> 12), n = idx & 4095;
    const float* P = which ? colsumP : rowsumP;
    float s = 0.f;
    for (int mt = 0; mt < 32; ++mt) s += P[(size_t)(bb * 32 + mt) * 4096 + n];
    (which ? Lcol : Lrow)[bb * 4096 + n] = logf(s);
}

// ---------------- scan: 256-thr blocks, 4 waves x 2 rows, LDS Lc + LDS colmax,
// nontemporal sim loads (no reuse). 512 stripes/batch.
__global__ __launch_bounds__(256) void scan_kernel(
    const float* __restrict__ simG,
    const float* __restrict__ Lrow, const float* __restrict__ Lcol,
    float* __restrict__ kvR, float* __restrict__ cvR, int* __restrict__ jR,
    unsigned* __restrict__ colPartU, int b0)
{
    __shared__ float    shLc[4096];          // 16 KB
    __shared__ unsigned colu[4096];          // 16 KB
    const int t = threadIdx.x, wave = t >> 6, lane = t & 63;
    const int blk = blockIdx.x;              // 0 .. CB*512-1
    const int bbl = blk >> 9, stripe = blk & 511;
    const int bb = b0 + bbl;
    const int row0 = stripe * 8;

    const float* LcB = Lcol + bb * Mm;
    for (int i = t; i < 4096; i += 256) { shLc[i] = LcB[i]; colu[i] = 0u; }
    __syncthreads();

    f32x4 cmax[16];
#pragma unroll
    for (int c = 0; c < 16; ++c) cmax[c] = (f32x4)(-INFINITY);

    for (int r = 0; r < 2; ++r) {
        const int rloc = row0 + wave * 2 + r;
        const float* rowp = simG + (size_t)(bbl * Nn + rloc) * Mm;
        const int n = bb * Nn + rloc;
        const float Ln = Lrow[n];
        const float cbias = -40.f - Ln;
        float bk = -INFINITY, bc = -INFINITY;
        int bm = 0x7fffffff;
#pragma unroll 4
        for (int c = 0; c < 16; ++c) {
            f32x4 s4  = __builtin_nontemporal_load((const f32x4*)&rowp[4 * (c * 64 + lane)]);
            f32x4 lc4 = *(const f32x4*)&shLc[4 * (c * 64 + lane)];
            float cv0 = fmaf(40.f, s4.x, cbias);
            float cv1 = fmaf(40.f, s4.y, cbias);
            float cv2 = fmaf(40.f, s4.z, cbias);
            float cv3 = fmaf(40.f, s4.w, cbias);
            cmax[c].x = fmaxf(cmax[c].x, cv0);
            cmax[c].y = fmaxf(cmax[c].y, cv1);
            cmax[c].z = fmaxf(cmax[c].z, cv2);
            cmax[c].w = fmaxf(cmax[c].w, cv3);
            const int mb = 4 * (c * 64 + lane);
            float kv0 = cv0 - lc4.x;
            float kv1 = cv1 - lc4.y;
            float kv2 = cv2 - lc4.z;
            float kv3 = cv3 - lc4.w;
            if (kv0 > bk) { bk = kv0; bm = mb;     bc = cv0; }
            if (kv1 > bk) { bk = kv1; bm = mb + 1; bc = cv1; }
            if (kv2 > bk) { bk = kv2; bm = mb + 2; bc = cv2; }
            if (kv3 > bk) { bk = kv3; bm = mb + 3; bc = cv3; }
        }
#pragma unroll
        for (int sh = 1; sh < 64; sh <<= 1) {
            float okv = __shfl_xor(bk, sh, 64);
            int   om  = __shfl_xor(bm, sh, 64);
            float ocv = __shfl_xor(bc, sh, 64);
            if (okv > bk || (okv == bk && om < bm)) { bk = okv; bm = om; bc = ocv; }
        }
        if (lane == 0) { kvR[n] = bk; cvR[n] = bc; jR[n] = bm; }
    }
    // merge 4 waves' colmax via LDS atomics (encf monotone), write one stripe
#pragma unroll
    for (int c = 0; c < 16; ++c) {
        const int mb = 4 * (c * 64 + lane);
        atomicMax(&colu[mb],     encf(cmax[c].x));
        atomicMax(&colu[mb + 1], encf(cmax[c].y));
        atomicMax(&colu[mb + 2], encf(cmax[c].z));
        atomicMax(&colu[mb + 3], encf(cmax[c].w));
    }
    __syncthreads();
    unsigned* cp = colPartU + (size_t)blk * 4096;
    for (int i = t; i < 4096; i += 256) cp[i] = colu[i];
}

// ---------------- column reduce: 512 stripes -> colMaxU (4 chunks of 128) ----------
__global__ __launch_bounds__(256) void colreduce_kernel(
    const unsigned* __restrict__ colPartU, unsigned* __restrict__ colMaxU, int b0)
{
    const int tid = blockIdx.x * 256 + threadIdx.x;  // 0 .. CB*16384-1
    const int bbl = tid >> 14;
    const int rem = tid & 16383;
    const int m = rem & 4095, sc = rem >> 12;        // sc in 0..3
    const int s0 = sc * 128;
    unsigned mx = 0u;
    const unsigned* p = colPartU + ((size_t)(bbl << 9) + s0) * 4096 + m;
    for (int s = 0; s < 128; ++s) { unsigned v = p[(size_t)s * 4096]; if (v > mx) mx = v; }
    atomicMax(&colMaxU[(size_t)(b0 + bbl) * Mm + m], mx);
}

// ---------------- validate rows ----------------
__global__ __launch_bounds__(256) void validate_kernel(
    const float* __restrict__ kvR, const float* __restrict__ cvR,
    const int* __restrict__ jR, const unsigned* __restrict__ colMaxU,
    float* __restrict__ outJ, int* __restrict__ v1)
{
    const float LOG_THR = -4.605170185988091f;   // ln(0.01)
    const int p = blockIdx.x * 256 + threadIdx.x;
    const int bb = p >> 12;
    const int j = jR[p];
    const float kv = kvR[p], cv = cvR[p];
    const float cm = decf(colMaxU[(size_t)bb * Mm + j]);
    const int ok = (kv > LOG_THR) && (cv >= cm);
    outJ[p] = (float)j;
    v1[p] = ok;
}

// ---------------- finalize rows (fallback path) ----------------
__global__ __launch_bounds__(256) void finalize_kernel(
    const float* __restrict__ rkey, const int* __restrict__ rmArr,
    const float* __restrict__ rcvArr, const unsigned* __restrict__ cmU,
    float* __restrict__ outJ, int* __restrict__ jIdx, int* __restrict__ v1)
{
    const float LOG_THR = -4.605170185988091f;
    int p = blockIdx.x * 256 + threadIdx.x;
    int bb = p >> 12, n = p & 4095;
    float bk = -INFINITY, bc = -INFINITY;
    int bm = 0;
    for (int mt = 0; mt < 32; ++mt) {
        size_t idx = (size_t)(bb * 32 + mt) * Nn + n;
        float k = rkey[idx];
        if (k > bk) { bk = k; bm = rmArr[idx]; bc = rcvArr[idx]; }
    }
    unsigned u = 0u;
    for (int nt = 0; nt < 32; ++nt) {
        unsigned c = cmU[(size_t)(bb * 32 + nt) * Mm + bm];
        if (c > u) u = c;
    }
    float cm = decf(u);
    int ok = (bk > LOG_THR) && (bc >= cm);
    outJ[p] = (float)bm;
    jIdx[p] = bm;
    v1[p]   = ok;
}

// ---------------- affine head ----------------
__global__ __launch_bounds__(256) void affine_kernel(
    const float* __restrict__ descA, const float* __restrict__ descB,
    const float* __restrict__ kpA, const float* __restrict__ kpB,
    const float* __restrict__ W, const float* __restrict__ bvec,
    const int* __restrict__ jIdx, const int* __restrict__ v1,
    float* __restrict__ outA, float* __restrict__ outB, float* __restrict__ outV)
{
    __shared__ float Ws[D0c * Kc];
    __shared__ float sbuf[4][4][D0c];
    const int t = threadIdx.x, wave = t >> 6, lane = t & 63;
    for (int i = t; i < D0c * Kc; i += 256) Ws[i] = W[i];
    const float bl = bvec[lane];
    __syncthreads();

    float* s0A = sbuf[wave][0];
    float* s1A = sbuf[wave][1];
    float* s0B = sbuf[wave][2];
    float* s1B = sbuf[wave][3];

    for (int p = 0; p < 8; ++p) {
        const int point = blockIdx.x * 32 + wave * 8 + p;
        const int bb = point >> 12;
        const int j = jIdx[point];
        const float* da = descA + (size_t)point * Dd;
        const float* db = descB + (size_t)(bb * Mm + j) * Dd;
        s0A[lane] = da[lane];       s0A[64 + lane] = da[64 + lane];
        s1A[lane] = da[128 + lane]; s1A[64 + lane] = da[192 + lane];
        s0B[lane] = db[lane];       s0B[64 + lane] = db[64 + lane];
        s1B[lane] = db[128 + lane]; s1B[64 + lane] = db[192 + lane];
        __syncthreads();

        float xa = bl, xb = bl;
#pragma unroll 8
        for (int d = 0; d < 128; ++d) {
            float w_ = Ws[d * 64 + lane];
            xa = fmaf(s0A[d], w_, xa);
            xb = fmaf(s0B[d], w_, xb);
        }
        float wa = softplusf(xa), wb = softplusf(xb);
        float w = sqrtf(wa * wb);
        float x0 = s1A[2 * lane], x1 = s1A[2 * lane + 1];
        float y0 = s1B[2 * lane], y1 = s1B[2 * lane + 1];
        float g00 = w * x0 * x0, g01 = w * x0 * x1, g11 = w * x1 * x1;
        float c00 = w * y0 * x0, c01 = w * y0 * x1;
        float c10 = w * y1 * x0, c11 = w * y1 * x1;
#pragma unroll
        for (int m = 32; m; m >>= 1) {
            g00 += __shfl_xor(g00, m, 64); g01 += __shfl_xor(g01, m, 64); g11 += __shfl_xor(g11, m, 64);
            c00 += __shfl_xor(c00, m, 64); c01 += __shfl_xor(c01, m, 64);
            c10 += __shfl_xor(c10, m, 64); c11 += __shfl_xor(c11, m, 64);
        }
        if (lane == 0) {
            g00 += 1e-6f; g11 += 1e-6f;
            float det = g00 * g11 - g01 * g01;
            float e00 = (c00 * g11 - c01 * g01) / det;
            float e01 = (c01 * g00 - c00 * g01) / det;
            float e10 = (c10 * g11 - c11 * g01) / det;
            float e11 = (c11 * g00 - c10 * g01) / det;
            float m00 = e00 * e00 + e10 * e10;
            float m01 = e00 * e01 + e10 * e11;
            float m11 = e01 * e01 + e11 * e11;
            float tr = m00 + m11;
            float dm = m00 * m11 - m01 * m01;
            float disc = sqrtf(fmaxf(0.25f * tr * tr - dm, 0.f));
            float lhi = 0.5f * tr + disc;
            float llo = fmaxf(0.5f * tr - disc, 0.f);
            float shi = sqrtf(lhi), slo = sqrtf(llo);
            float sdet = e00 * e11 - e01 * e10;
            int good = isfinite(shi + slo) && (shi < 3.0f) && (slo > 0.33333334f) && (sdet > 0.f);
            int valid = v1[point] && good;
            outA[2 * point]     = kpA[2 * point];
            outA[2 * point + 1] = kpA[2 * point + 1];
            const float* kb = kpB + (size_t)(bb * Mm + j) * 2;
            outB[2 * point]     = kb[0];
            outB[2 * point + 1] = kb[1];
            outV[point] = valid ? 1.f : 0.f;
        }
        __syncthreads();
    }
}

extern "C" void kernel_launch(void* const* d_in, const int* in_sizes, int n_in,
                              void* d_out, int out_size, void* d_ws, size_t ws_size,
                              hipStream_t stream) {
    const float* kpA = (const float*)d_in[0];
    const float* dA  = (const float*)d_in[1];
    const float* kpB = (const float*)d_in[2];
    const float* dB  = (const float*)d_in[3];
    const float* W   = (const float*)d_in[4];
    const float* bl  = (const float*)d_in[5];
    float* out = (float*)d_out;

    char* ws = (char*)d_ws;
    _Float16* Ah = (_Float16*)ws;  ws += 8388608;
    _Float16* Al = (_Float16*)ws;  ws += 8388608;
    _Float16* Bh = (_Float16*)ws;  ws += 8388608;
    _Float16* Bl = (_Float16*)ws;  ws += 8388608;
    float*    rowsumP = (float*)ws;    ws += 2097152;
    float*    colsumP = (float*)ws;    ws += 2097152;
    float*    Lrow    = (float*)ws;    ws += 65536;
    float*    Lcol    = (float*)ws;    ws += 65536;
    int*      jIdx    = (int*)ws;      ws += 65536;
    int*      v1      = (int*)ws;      ws += 65536;
    float*    kvR     = (float*)ws;    ws += 65536;
    float*    cvR     = (float*)ws;    ws += 65536;
    unsigned* colMaxU = (unsigned*)ws; ws += 65536;
    char*     big     = ws;

    const size_t base = (size_t)(big - (char*)d_ws);

    // fallback layout (overlays big region)
    float*    rkey  = (float*)big;
    int*      rmArr = (int*)(big + 2097152);
    float*    rcvArr= (float*)(big + 4194304);
    unsigned* cmU   = (unsigned*)(big + 6291456);

    float* outA = out;               // matches_A : 32768
    float* outB = out + 32768;       // matches_B : 32768
    float* outJ = out + 65536;       // j (as f32): 16384
    float* outV = out + 81920;       // valid     : 16384

    // per-chunk need: CB*64 MB sim + CB*8 MB colPart
    const size_t per = 67108864ull + 8388608ull;
    int CB = 0;
    if      (ws_size >= base + 2 * per) CB = 2;
    else if (ws_size >= base + 1 * per) CB = 1;

    prep_kernel<<<dim3(4096, 2), 256, 0, stream>>>(dA, dB, Ah, Al, Bh, Bl, colMaxU);

    if (CB) {
        float*    simG     = (float*)big;
        unsigned* colPartU = (unsigned*)(big + (size_t)CB * 67108864);
        for (int b0 = 0; b0 < Bb; b0 += CB) {
            sim_kernel<0, 1><<<dim3(32, 32, CB), 256, 0, stream>>>(
                Ah, Al, Bh, Bl, nullptr, nullptr, rowsumP, colsumP,
                nullptr, nullptr, nullptr, nullptr, simG, b0);
            logsum_kernel<<<32 * CB, 256, 0, stream>>>(rowsumP, colsumP, Lrow, Lcol, b0, CB);
            scan_kernel<<<512 * CB, 256, 0, stream>>>(simG, Lrow, Lcol, kvR, cvR, jIdx, colPartU, b0);
            colreduce_kernel<<<64 * CB, 256, 0, stream>>>(colPartU, colMaxU, b0);
        }
        validate_kernel<<<64, 256, 0, stream>>>(kvR, cvR, jIdx, colMaxU, outJ, v1);
    } else {
        sim_kernel<0, 0><<<dim3(32, 32, Bb), 256, 0, stream>>>(
            Ah, Al, Bh, Bl, nullptr, nullptr, rowsumP, colsumP,
            nullptr, nullptr, nullptr, nullptr, nullptr, 0);
        logsum_kernel<<<32 * Bb, 256, 0, stream>>>(rowsumP, colsumP, Lrow, Lcol, 0, Bb);
        sim_kernel<1, 0><<<dim3(32, 32, Bb), 256, 0, stream>>>(
            Ah, Al, Bh, Bl, Lrow, Lcol, nullptr, nullptr,
            rkey, rmArr, rcvArr, cmU, nullptr, 0);
        finalize_kernel<<<64, 256, 0, stream>>>(rkey, rmArr, rcvArr, cmU, outJ, jIdx, v1);
    }
    affine_kernel<<<512, 256, 0, stream>>>(dA, dB, kpA, kpB, W, bl, jIdx, v1, outA, outB, outV);
}

// Round 13
// 339.122 us; speedup vs baseline: 1.3723x; 1.3723x over previous
//
#include <hip/hip_runtime.h>
#include <math.h>

#define Bb   4
#define Nn   4096
#define Mm   4096
#define Dd   256
#define D0c  128
#define Kc   64

typedef _Float16 half8 __attribute__((ext_vector_type(8)));
typedef float    f32x4 __attribute__((ext_vector_type(4)));

__device__ __forceinline__ unsigned encf(float f) {
    unsigned u = __float_as_uint(f);
    return (u & 0x80000000u) ? ~u : (u | 0x80000000u);
}
__device__ __forceinline__ float decf(unsigned u) {
    return (u & 0x80000000u) ? __uint_as_float(u ^ 0x80000000u) : __uint_as_float(~u);
}
__device__ __forceinline__ float softplusf(float x) {
    return fmaxf(x, 0.f) + log1pf(expf(-fabsf(x)));
}
__device__ __forceinline__ void gl_lds16(const _Float16* g, _Float16* l) {
    __builtin_amdgcn_global_load_lds((const __attribute__((address_space(1))) void*)g,
                                     (__attribute__((address_space(3))) void*)l, 16, 0, 0);
}

// ---------------- prep: normalize rows, split fp16 hi/lo, tiled layout -------------
__global__ __launch_bounds__(256) void prep_kernel(
    const float* __restrict__ dA, const float* __restrict__ dB,
    _Float16* __restrict__ Ah, _Float16* __restrict__ Al,
    _Float16* __restrict__ Bh, _Float16* __restrict__ Bl)
{
    const int t = threadIdx.x, wave = t >> 6, lane = t & 63;
    const int row = blockIdx.x * 4 + wave;           // 0..16383
    const float* src = blockIdx.y ? dB : dA;
    _Float16* dh = blockIdx.y ? Bh : Ah;
    _Float16* dl = blockIdx.y ? Bl : Al;
    const float4 v = *(const float4*)&src[(size_t)row * Dd + lane * 4];
    float ss = v.x * v.x + v.y * v.y + v.z * v.z + v.w * v.w;
#pragma unroll
    for (int m = 32; m; m >>= 1) ss += __shfl_xor(ss, m, 64);
    const float inv = 1.0f / sqrtf(ss);
    float x[4] = {v.x * inv, v.y * inv, v.z * inv, v.w * inv};
    union { _Float16 h[4]; uint2 u; } ph, pl;
#pragma unroll
    for (int i = 0; i < 4; i++) {
        _Float16 h = (_Float16)x[i];
        ph.h[i] = h;
        pl.h[i] = (_Float16)((x[i] - (float)h) * 4096.f);
    }
    const size_t toff = (size_t)(row >> 7) * 32768
                      + (size_t)(lane >> 3) * 4096
                      + (size_t)((lane >> 1) & 3) * 1024
                      + (size_t)(row & 127) * 8 + (lane & 1) * 4;
    *(uint2*)&dh[toff] = ph.u;
    *(uint2*)&dl[toff] = pl.u;
}

// ---------------- MFMA sim kernel ----------------
// PB=0: row/col exp-sum partials (+ optional nt-STORE of dot matrix for chunk)
// PB=1: argmax pass (fallback path only)
template<int PB, int STORE>
__global__ __launch_bounds__(256, 2) void sim_kernel(
    const _Float16* __restrict__ Ah, const _Float16* __restrict__ Al,
    const _Float16* __restrict__ Bh, const _Float16* __restrict__ Bl,
    const float* __restrict__ Lrow_g, const float* __restrict__ Lcol_g,
    float* __restrict__ rowsumP, float* __restrict__ colsumP,
    float* __restrict__ rkey, int* __restrict__ rmArr, float* __restrict__ rcvArr,
    unsigned* __restrict__ cmU, float* __restrict__ simG, int b0)
{
    __shared__ _Float16 lds[4][4][128][8];   // 32 KB
    __shared__ float    colp[128];
    __shared__ unsigned colu[128];
    __shared__ float    shL[128], shLc[128];

    const int t = threadIdx.x;
    const int wave = t >> 6, lane = t & 63;
    const int mt = blockIdx.x, nt = blockIdx.y, bbl = blockIdx.z;
    const int bb = b0 + bbl;
    const int n0 = nt * 128, m0 = mt * 128;

    if (PB) {
        if (t < 128) {
            shL[t]  = Lrow_g[bb * Nn + n0 + t];
            shLc[t] = Lcol_g[bb * Mm + m0 + t];
            colu[t] = 0u;
        }
    } else {
        if (t < 128) colp[t] = 0.f;
    }

    const _Float16* gb;
    {
        const size_t offA = (size_t)(bb * Nn + n0) * Dd;
        const size_t offB = (size_t)(bb * Mm + m0) * Dd;
        if      (wave == 0) gb = Ah + offA;
        else if (wave == 1) gb = Al + offA;
        else if (wave == 2) gb = Bh + offB;
        else                gb = Bl + offB;
    }

    f32x4 acc1[2][8], acc2[2][8];
#pragma unroll
    for (int ti = 0; ti < 2; ti++)
#pragma unroll
        for (int tj = 0; tj < 8; tj++) { acc1[ti][tj] = (f32x4)0.f; acc2[ti][tj] = (f32x4)0.f; }

    const int quad = lane >> 4, l15 = lane & 15;
    _Float16* ldsw = &lds[wave][0][0][0];

    for (int kc8 = 0; kc8 < 8; ++kc8) {
        const _Float16* gsrc = gb + kc8 * 4096;
#pragma unroll
        for (int q = 0; q < 8; ++q)
            gl_lds16(gsrc + q * 512 + lane * 8, ldsw + q * 512);
        __syncthreads();

        half8 afh[2], afl[2];
        afh[0] = *(const half8*)&lds[0][quad][wave * 32 + l15][0];
        afh[1] = *(const half8*)&lds[0][quad][wave * 32 + 16 + l15][0];
        afl[0] = *(const half8*)&lds[1][quad][wave * 32 + l15][0];
        afl[1] = *(const half8*)&lds[1][quad][wave * 32 + 16 + l15][0];
#pragma unroll
        for (int tj = 0; tj < 8; ++tj) {
            half8 bh = *(const half8*)&lds[2][quad][tj * 16 + l15][0];
            half8 bl = *(const half8*)&lds[3][quad][tj * 16 + l15][0];
#pragma unroll
            for (int ti = 0; ti < 2; ++ti) {
                acc1[ti][tj] = __builtin_amdgcn_mfma_f32_16x16x32_f16(afh[ti], bh, acc1[ti][tj], 0, 0, 0);
                acc2[ti][tj] = __builtin_amdgcn_mfma_f32_16x16x32_f16(afh[ti], bl, acc2[ti][tj], 0, 0, 0);
                acc2[ti][tj] = __builtin_amdgcn_mfma_f32_16x16x32_f16(afl[ti], bh, acc2[ti][tj], 0, 0, 0);
            }
        }
        __syncthreads();
    }

    if (!PB) {
        float rp[8] = {0.f}, cp[8] = {0.f};
#pragma unroll
        for (int ti = 0; ti < 2; ++ti)
#pragma unroll
            for (int tj = 0; tj < 8; ++tj)
#pragma unroll
                for (int r = 0; r < 4; ++r) {
                    float dot = fmaf(acc2[ti][tj][r], 2.44140625e-4f, acc1[ti][tj][r]);
                    acc1[ti][tj][r] = dot;
                    float e = __expf(fmaf(20.f, dot, -20.f));
                    rp[ti * 4 + r] += e;
                    cp[tj] += e;
                }
#pragma unroll
        for (int i = 0; i < 8; ++i)
#pragma unroll
            for (int m = 1; m < 16; m <<= 1) rp[i] += __shfl_xor(rp[i], m, 64);
        if (l15 == 0) {
#pragma unroll
            for (int ti = 0; ti < 2; ++ti)
#pragma unroll
                for (int r = 0; r < 4; ++r)
                    rowsumP[(size_t)(bb * 32 + mt) * Nn + n0 + wave * 32 + ti * 16 + quad * 4 + r] = rp[ti * 4 + r];
        }
#pragma unroll
        for (int tj = 0; tj < 8; ++tj) {
            cp[tj] += __shfl_xor(cp[tj], 16, 64);
            cp[tj] += __shfl_xor(cp[tj], 32, 64);
        }
        if (quad == 0) {
#pragma unroll
            for (int tj = 0; tj < 8; ++tj) atomicAdd(&colp[tj * 16 + l15], cp[tj]);
        }
        __syncthreads();
        if (t < 128) colsumP[(size_t)(bb * 32 + nt) * Mm + m0 + t] = colp[t];
        if (STORE) {
            // nontemporal: drain to HBM during this (MFMA-bound) kernel
            float* base = simG + ((size_t)bbl * Nn + n0) * Mm + m0;
#pragma unroll
            for (int ti = 0; ti < 2; ++ti)
#pragma unroll
                for (int r = 0; r < 4; ++r) {
                    float* rowp = base + (size_t)(wave * 32 + ti * 16 + quad * 4 + r) * Mm;
#pragma unroll
                    for (int tj = 0; tj < 8; ++tj)
                        __builtin_nontemporal_store(acc1[ti][tj][r], rowp + tj * 16 + l15);
                }
        }
    } else {
        float Lr[8];
#pragma unroll
        for (int ti = 0; ti < 2; ++ti)
#pragma unroll
            for (int r = 0; r < 4; ++r)
                Lr[ti * 4 + r] = shL[wave * 32 + ti * 16 + quad * 4 + r];

        float bk[8], bc[8];
        int bm[8];
        unsigned cu[8];
#pragma unroll
        for (int i = 0; i < 8; i++) { bk[i] = -INFINITY; bc[i] = -INFINITY; bm[i] = 0x7fffffff; }
#pragma unroll
        for (int j = 0; j < 8; j++) cu[j] = 0u;

#pragma unroll
        for (int ti = 0; ti < 2; ++ti)
#pragma unroll
            for (int tj = 0; tj < 8; ++tj)
#pragma unroll
                for (int r = 0; r < 4; ++r) {
                    float dot = fmaf(acc2[ti][tj][r], 2.44140625e-4f, acc1[ti][tj][r]);
                    float cv = fmaf(40.f, dot, -40.f - Lr[ti * 4 + r]);
                    float kv = cv - shLc[tj * 16 + l15];
                    const int i = ti * 4 + r;
                    if (kv > bk[i]) { bk[i] = kv; bm[i] = m0 + tj * 16 + l15; bc[i] = cv; }
                    unsigned e = encf(cv);
                    if (e > cu[tj]) cu[tj] = e;
                }
#pragma unroll
        for (int i = 0; i < 8; ++i) {
#pragma unroll
            for (int m = 1; m < 16; m <<= 1) {
                float okv = __shfl_xor(bk[i], m, 64);
                int   om  = __shfl_xor(bm[i], m, 64);
                float ocv = __shfl_xor(bc[i], m, 64);
                if (okv > bk[i] || (okv == bk[i] && om < bm[i])) { bk[i] = okv; bm[i] = om; bc[i] = ocv; }
            }
        }
        if (l15 == 0) {
#pragma unroll
            for (int ti = 0; ti < 2; ++ti)
#pragma unroll
                for (int r = 0; r < 4; ++r) {
                    const int i = ti * 4 + r;
                    size_t idx = (size_t)(bb * 32 + mt) * Nn + n0 + wave * 32 + ti * 16 + quad * 4 + r;
                    rkey[idx] = bk[i]; rmArr[idx] = bm[i]; rcvArr[idx] = bc[i];
                }
        }
#pragma unroll
        for (int tj = 0; tj < 8; ++tj) {
            unsigned o = __shfl_xor(cu[tj], 16, 64); if (o > cu[tj]) cu[tj] = o;
            o = __shfl_xor(cu[tj], 32, 64); if (o > cu[tj]) cu[tj] = o;
        }
        if (quad == 0) {
#pragma unroll
            for (int tj = 0; tj < 8; ++tj) atomicMax(&colu[tj * 16 + l15], cu[tj]);
        }
        __syncthreads();
        if (t < 128) cmU[(size_t)(bb * 32 + nt) * Mm + m0 + t] = colu[t];
    }
}

// ---------------- reduce partials -> L = log(rowsum), Lc = log(colsum), chunked -----
__global__ __launch_bounds__(256) void logsum_kernel(
    const float* __restrict__ rowsumP, const float* __restrict__ colsumP,
    float* __restrict__ Lrow, float* __restrict__ Lcol, int b0, int CB)
{
    int t = blockIdx.x * 256 + threadIdx.x;
    int half = CB * 4096;
    int which = t >= half;
    int idx = which ? (t - half) : t;
    int bb = b0 + (idx >> 12), n = idx & 4095;
    const float* P = which ? colsumP : rowsumP;
    float s = 0.f;
    for (int mt = 0; mt < 32; ++mt) s += P[(size_t)(bb * 32 + mt) * 4096 + n];
    (which ? Lcol : Lrow)[bb * 4096 + n] = logf(s);
}

// ---------------- scan v5: block = 32 rows x 1024 cols (quarter), prefetch dbuf ----
// blk -> bbl = blk>>9 ; stripe = (blk&511)>>2 (0..127, 32 rows) ; q = blk&3 (quarter)
// wave handles 8 rows, all 64 lanes on the same row (lane covers 16 consecutive cols
// in 4 f32x4 chunks spaced 256 floats). Per-(row,quarter) candidate -> kvP/cvP/jP.
// Block colmax over its 1024 cols via LDS atomicMax(encf) -> colPart stripe (4 KB).
__global__ __launch_bounds__(256) void scan_kernel(
    const float* __restrict__ simG,
    const float* __restrict__ Lrow, const float* __restrict__ Lcol,
    float* __restrict__ kvP, float* __restrict__ cvP, int* __restrict__ jP,
    unsigned* __restrict__ colPartU, int b0)
{
    __shared__ unsigned colu[1024];          // 4 KB
    const int t = threadIdx.x, wave = t >> 6, lane = t & 63;
    const int blk = blockIdx.x;              // 0 .. CB*512-1
    const int bbl = blk >> 9;
    const int r9 = blk & 511;
    const int stripe = r9 >> 2, q = r9 & 3;
    const int bb = b0 + bbl;
    const int col0 = q * 1024;
    const int row0 = stripe * 32 + wave * 8;

    for (int i = t; i < 1024; i += 256) colu[i] = 0u;
    __syncthreads();

    f32x4 Lc4[4], cmax[4];
    const float* LcB = Lcol + bb * Mm + col0;
#pragma unroll
    for (int c = 0; c < 4; ++c) {
        Lc4[c] = *(const f32x4*)&LcB[c * 256 + lane * 4];
        cmax[c] = (f32x4)(-INFINITY);
    }

    const float* rowbase = simG + (size_t)(bbl * Nn + row0) * Mm + col0;
    f32x4 cur[4], nxt[4];
#pragma unroll
    for (int c = 0; c < 4; ++c)
        cur[c] = __builtin_nontemporal_load((const f32x4*)&rowbase[c * 256 + lane * 4]);

    for (int r = 0; r < 8; ++r) {
        if (r < 7) {
            const float* nrow = rowbase + (size_t)(r + 1) * Mm;
#pragma unroll
            for (int c = 0; c < 4; ++c)
                nxt[c] = __builtin_nontemporal_load((const f32x4*)&nrow[c * 256 + lane * 4]);
        }
        const int n = bb * Nn + row0 + r;
        const float Ln = Lrow[n];
        const float cbias = -40.f - Ln;
        float bk = -INFINITY, bc = -INFINITY;
        int bm = 0x7fffffff;
#pragma unroll
        for (int c = 0; c < 4; ++c) {
            float cv0 = fmaf(40.f, cur[c].x, cbias);
            float cv1 = fmaf(40.f, cur[c].y, cbias);
            float cv2 = fmaf(40.f, cur[c].z, cbias);
            float cv3 = fmaf(40.f, cur[c].w, cbias);
            cmax[c].x = fmaxf(cmax[c].x, cv0);
            cmax[c].y = fmaxf(cmax[c].y, cv1);
            cmax[c].z = fmaxf(cmax[c].z, cv2);
            cmax[c].w = fmaxf(cmax[c].w, cv3);
            const int mb = col0 + c * 256 + lane * 4;
            float kv0 = cv0 - Lc4[c].x;
            float kv1 = cv1 - Lc4[c].y;
            float kv2 = cv2 - Lc4[c].z;
            float kv3 = cv3 - Lc4[c].w;
            if (kv0 > bk) { bk = kv0; bm = mb;     bc = cv0; }
            if (kv1 > bk) { bk = kv1; bm = mb + 1; bc = cv1; }
            if (kv2 > bk) { bk = kv2; bm = mb + 2; bc = cv2; }
            if (kv3 > bk) { bk = kv3; bm = mb + 3; bc = cv3; }
        }
        // full-wave lexicographic reduce (overlaps prefetch latency)
#pragma unroll
        for (int sh = 1; sh < 64; sh <<= 1) {
            float okv = __shfl_xor(bk, sh, 64);
            int   om  = __shfl_xor(bm, sh, 64);
            float ocv = __shfl_xor(bc, sh, 64);
            if (okv > bk || (okv == bk && om < bm)) { bk = okv; bm = om; bc = ocv; }
        }
        if (lane == 0) {
            size_t o = ((size_t)bb * Nn + row0 + r) * 4 + q;
            kvP[o] = bk; cvP[o] = bc; jP[o] = bm;
        }
#pragma unroll
        for (int c = 0; c < 4; ++c) cur[c] = nxt[c];
    }
    // merge the 4 waves' (32 rows') colmax in LDS, one coalesced 4 KB stripe write
#pragma unroll
    for (int c = 0; c < 4; ++c) {
        const int mb = c * 256 + lane * 4;
        atomicMax(&colu[mb],     encf(cmax[c].x));
        atomicMax(&colu[mb + 1], encf(cmax[c].y));
        atomicMax(&colu[mb + 2], encf(cmax[c].z));
        atomicMax(&colu[mb + 3], encf(cmax[c].w));
    }
    __syncthreads();
    unsigned* cp = colPartU + (size_t)blk * 1024;
    for (int i = t; i < 1024; i += 256) cp[i] = colu[i];
}

// ---------------- column reduce: 128 stripes -> colMaxF (unique writer, no atomics) -
__global__ __launch_bounds__(256) void colreduce_kernel(
    const unsigned* __restrict__ colPartU, float* __restrict__ colMaxF, int b0)
{
    const int tid = blockIdx.x * 256 + threadIdx.x;  // 0 .. CB*4096-1
    const int bbl = tid >> 12;
    const int m = tid & 4095;
    const int q = m >> 10, ml = m & 1023;
    unsigned mx = 0u;
    for (int s = 0; s < 128; ++s) {
        unsigned v = colPartU[((size_t)(bbl * 512 + s * 4 + q)) * 1024 + ml];
        if (v > mx) mx = v;
    }
    colMaxF[(size_t)(b0 + bbl) * Mm + m] = decf(mx);
}

// ---------------- validate rows: merge 4 quarter-candidates, gate ----------------
__global__ __launch_bounds__(256) void validate_kernel(
    const float* __restrict__ kvP, const float* __restrict__ cvP,
    const int* __restrict__ jP, const float* __restrict__ colMaxF,
    float* __restrict__ outJ, int* __restrict__ jIdx, int* __restrict__ v1)
{
    const float LOG_THR = -4.605170185988091f;   // ln(0.01)
    const int p = blockIdx.x * 256 + threadIdx.x;
    const int bb = p >> 12;
    float bk = -INFINITY, bc = -INFINITY;
    int bm = 0x7fffffff;
#pragma unroll
    for (int q = 0; q < 4; ++q) {
        size_t o = (size_t)p * 4 + q;
        float k = kvP[o];
        int   m = jP[o];
        if (k > bk || (k == bk && m < bm)) { bk = k; bm = m; bc = cvP[o]; }
    }
    const float cm = colMaxF[(size_t)bb * Mm + bm];
    const int ok = (bk > LOG_THR) && (bc >= cm);
    outJ[p] = (float)bm;
    jIdx[p] = bm;
    v1[p] = ok;
}

// ---------------- finalize rows (fallback path) ----------------
__global__ __launch_bounds__(256) void finalize_kernel(
    const float* __restrict__ rkey, const int* __restrict__ rmArr,
    const float* __restrict__ rcvArr, const unsigned* __restrict__ cmU,
    float* __restrict__ outJ, int* __restrict__ jIdx, int* __restrict__ v1)
{
    const float LOG_THR = -4.605170185988091f;
    int p = blockIdx.x * 256 + threadIdx.x;
    int bb = p >> 12, n = p & 4095;
    float bk = -INFINITY, bc = -INFINITY;
    int bm = 0;
    for (int mt = 0; mt < 32; ++mt) {
        size_t idx = (size_t)(bb * 32 + mt) * Nn + n;
        float k = rkey[idx];
        if (k > bk) { bk = k; bm = rmArr[idx]; bc = rcvArr[idx]; }
    }
    unsigned u = 0u;
    for (int nt = 0; nt < 32; ++nt) {
        unsigned c = cmU[(size_t)(bb * 32 + nt) * Mm + bm];
        if (c > u) u = c;
    }
    float cm = decf(u);
    int ok = (bk > LOG_THR) && (bc >= cm);
    outJ[p] = (float)bm;
    jIdx[p] = bm;
    v1[p]   = ok;
}

// ---------------- affine head ----------------
__global__ __launch_bounds__(256) void affine_kernel(
    const float* __restrict__ descA, const float* __restrict__ descB,
    const float* __restrict__ kpA, const float* __restrict__ kpB,
    const float* __restrict__ W, const float* __restrict__ bvec,
    const int* __restrict__ jIdx, const int* __restrict__ v1,
    float* __restrict__ outA, float* __restrict__ outB, float* __restrict__ outV)
{
    __shared__ float Ws[D0c * Kc];
    __shared__ float sbuf[4][4][D0c];
    const int t = threadIdx.x, wave = t >> 6, lane = t & 63;
    for (int i = t; i < D0c * Kc; i += 256) Ws[i] = W[i];
    const float bl = bvec[lane];
    __syncthreads();

    float* s0A = sbuf[wave][0];
    float* s1A = sbuf[wave][1];
    float* s0B = sbuf[wave][2];
    float* s1B = sbuf[wave][3];

    for (int p = 0; p < 8; ++p) {
        const int point = blockIdx.x * 32 + wave * 8 + p;
        const int bb = point >> 12;
        const int j = jIdx[point];
        const float* da = descA + (size_t)point * Dd;
        const float* db = descB + (size_t)(bb * Mm + j) * Dd;
        s0A[lane] = da[lane];       s0A[64 + lane] = da[64 + lane];
        s1A[lane] = da[128 + lane]; s1A[64 + lane] = da[192 + lane];
        s0B[lane] = db[lane];       s0B[64 + lane] = db[64 + lane];
        s1B[lane] = db[128 + lane]; s1B[64 + lane] = db[192 + lane];
        __syncthreads();

        float xa = bl, xb = bl;
#pragma unroll 8
        for (int d = 0; d < 128; ++d) {
            float w_ = Ws[d * 64 + lane];
            xa = fmaf(s0A[d], w_, xa);
            xb = fmaf(s0B[d], w_, xb);
        }
        float wa = softplusf(xa), wb = softplusf(xb);
        float w = sqrtf(wa * wb);
        float x0 = s1A[2 * lane], x1 = s1A[2 * lane + 1];
        float y0 = s1B[2 * lane], y1 = s1B[2 * lane + 1];
        float g00 = w * x0 * x0, g01 = w * x0 * x1, g11 = w * x1 * x1;
        float c00 = w * y0 * x0, c01 = w * y0 * x1;
        float c10 = w * y1 * x0, c11 = w * y1 * x1;
#pragma unroll
        for (int m = 32; m; m >>= 1) {
            g00 += __shfl_xor(g00, m, 64); g01 += __shfl_xor(g01, m, 64); g11 += __shfl_xor(g11, m, 64);
            c00 += __shfl_xor(c00, m, 64); c01 += __shfl_xor(c01, m, 64);
            c10 += __shfl_xor(c10, m, 64); c11 += __shfl_xor(c11, m, 64);
        }
        if (lane == 0) {
            g00 += 1e-6f; g11 += 1e-6f;
            float det = g00 * g11 - g01 * g01;
            float e00 = (c00 * g11 - c01 * g01) / det;
            float e01 = (c01 * g00 - c00 * g01) / det;
            float e10 = (c10 * g11 - c11 * g01) / det;
            float e11 = (c11 * g00 - c10 * g01) / det;
            float m00 = e00 * e00 + e10 * e10;
            float m01 = e00 * e01 + e10 * e11;
            float m11 = e01 * e01 + e11 * e11;
            float tr = m00 + m11;
            float dm = m00 * m11 - m01 * m01;
            float disc = sqrtf(fmaxf(0.25f * tr * tr - dm, 0.f));
            float lhi = 0.5f * tr + disc;
            float llo = fmaxf(0.5f * tr - disc, 0.f);
            float shi = sqrtf(lhi), slo = sqrtf(llo);
            float sdet = e00 * e11 - e01 * e10;
            int good = isfinite(shi + slo) && (shi < 3.0f) && (slo > 0.33333334f) && (sdet > 0.f);
            int valid = v1[point] && good;
            outA[2 * point]     = kpA[2 * point];
            outA[2 * point + 1] = kpA[2 * point + 1];
            const float* kb = kpB + (size_t)(bb * Mm + j) * 2;
            outB[2 * point]     = kb[0];
            outB[2 * point + 1] = kb[1];
            outV[point] = valid ? 1.f : 0.f;
        }
        __syncthreads();
    }
}

extern "C" void kernel_launch(void* const* d_in, const int* in_sizes, int n_in,
                              void* d_out, int out_size, void* d_ws, size_t ws_size,
                              hipStream_t stream) {
    const float* kpA = (const float*)d_in[0];
    const float* dA  = (const float*)d_in[1];
    const float* kpB = (const float*)d_in[2];
    const float* dB  = (const float*)d_in[3];
    const float* W   = (const float*)d_in[4];
    const float* bl  = (const float*)d_in[5];
    float* out = (float*)d_out;

    char* ws = (char*)d_ws;
    _Float16* Ah = (_Float16*)ws;  ws += 8388608;
    _Float16* Al = (_Float16*)ws;  ws += 8388608;
    _Float16* Bh = (_Float16*)ws;  ws += 8388608;
    _Float16* Bl = (_Float16*)ws;  ws += 8388608;
    float*    rowsumP = (float*)ws;    ws += 2097152;
    float*    colsumP = (float*)ws;    ws += 2097152;
    float*    Lrow    = (float*)ws;    ws += 65536;
    float*    Lcol    = (float*)ws;    ws += 65536;
    int*      jIdx    = (int*)ws;      ws += 65536;
    int*      v1      = (int*)ws;      ws += 65536;
    float*    kvP     = (float*)ws;    ws += 262144;
    float*    cvP     = (float*)ws;    ws += 262144;
    int*      jP      = (int*)ws;      ws += 262144;
    float*    colMaxF = (float*)ws;    ws += 65536;
    char*     big     = ws;

    const size_t base = (size_t)(big - (char*)d_ws);

    // fallback layout (overlays big region)
    float*    rkey  = (float*)big;
    int*      rmArr = (int*)(big + 2097152);
    float*    rcvArr= (float*)(big + 4194304);
    unsigned* cmU   = (unsigned*)(big + 6291456);

    float* outA = out;               // matches_A : 32768
    float* outB = out + 32768;       // matches_B : 32768
    float* outJ = out + 65536;       // j (as f32): 16384
    float* outV = out + 81920;       // valid     : 16384

    // per-chunk need: CB*64 MB sim + CB*2 MB colPart
    const size_t per = 67108864ull + 2097152ull;
    int CB = 0;
    if      (ws_size >= base + 2 * per) CB = 2;
    else if (ws_size >= base + 1 * per) CB = 1;

    prep_kernel<<<dim3(4096, 2), 256, 0, stream>>>(dA, dB, Ah, Al, Bh, Bl);

    if (CB) {
        float*    simG     = (float*)big;
        unsigned* colPartU = (unsigned*)(big + (size_t)CB * 67108864);
        for (int b0 = 0; b0 < Bb; b0 += CB) {
            sim_kernel<0, 1><<<dim3(32, 32, CB), 256, 0, stream>>>(
                Ah, Al, Bh, Bl, nullptr, nullptr, rowsumP, colsumP,
                nullptr, nullptr, nullptr, nullptr, simG, b0);
            logsum_kernel<<<32 * CB, 256, 0, stream>>>(rowsumP, colsumP, Lrow, Lcol, b0, CB);
            scan_kernel<<<512 * CB, 256, 0, stream>>>(simG, Lrow, Lcol, kvP, cvP, jP, colPartU, b0);
            colreduce_kernel<<<16 * CB, 256, 0, stream>>>(colPartU, colMaxF, b0);
        }
        validate_kernel<<<64, 256, 0, stream>>>(kvP, cvP, jP, colMaxF, outJ, jIdx, v1);
    } else {
        sim_kernel<0, 0><<<dim3(32, 32, Bb), 256, 0, stream>>>(
            Ah, Al, Bh, Bl, nullptr, nullptr, rowsumP, colsumP,
            nullptr, nullptr, nullptr, nullptr, nullptr, 0);
        logsum_kernel<<<32 * Bb, 256, 0, stream>>>(rowsumP, colsumP, Lrow, Lcol, 0, Bb);
        sim_kernel<1, 0><<<dim3(32, 32, Bb), 256, 0, stream>>>(
            Ah, Al, Bh, Bl, Lrow, Lcol, nullptr, nullptr,
            rkey, rmArr, rcvArr, cmU, nullptr, 0);
        finalize_kernel<<<64, 256, 0, stream>>>(rkey, rmArr, rcvArr, cmU, outJ, jIdx, v1);
    }
    affine_kernel<<<512, 256, 0, stream>>>(dA, dB, kpA, kpB, W, bl, jIdx, v1, outA, outB, outV);
}